// Round 3
// baseline (261.162 us; speedup 1.0000x reference)
//
#include <hip/hip_runtime.h>

#define BDIM 128
#define T 200
#define E 64

__global__ __launch_bounds__(BDIM, 2) void din_kernel(
    const int* __restrict__ query,
    const int* __restrict__ keys,
    const float* __restrict__ emb,
    const float* __restrict__ w1,
    const float* __restrict__ b1,
    const float* __restrict__ w2,
    const float* __restrict__ b2,
    const float* __restrict__ dw1,
    const float* __restrict__ db1,
    const float* __restrict__ dw2,
    const float* __restrict__ db2,
    const float* __restrict__ ow,
    const float* __restrict__ ob,
    float* __restrict__ out)
{
    // sBig dual-use (barrier-separated):
    //   phase A (score): M[e][j] at stride 64, read as wave-broadcast float4
    //   phase C (interest): per-lane accum at stride 65 (conflict-free scalar)
    __shared__ __align__(16) float sBig[64 * 65];
    __shared__ __align__(16) float sU[64];
    __shared__ __align__(16) float sQ[64];
    __shared__ __align__(16) float sW2[64];
    __shared__ __align__(16) float sUP[BDIM];
    __shared__ float sRed[4];
    __shared__ float sInt[64];
    __shared__ float sD1[128];
    __shared__ float sD2[64];

    const int tid  = threadIdx.x;
    const int lane = tid & 63;
    const int wid  = tid >> 6;      // 0..1
    const int b    = blockIdx.x;

    // ---- query embedding row -> LDS; small vectors -> LDS ----
    const int qi = query[b];
    if (tid < 16) ((float4*)sQ)[tid] = ((const float4*)(emb + (size_t)qi * E))[tid];
    if (tid < 64) sW2[tid] = w2[tid];
    const float b2v = b2[0];

    // two t's per lane: t0 = tid (always < 200), t1 = tid + 128 (valid if < 200)
    const int  t0      = tid;
    const int  t1      = tid + BDIM;
    const bool t1valid = (t1 < T);
    const int  t1c     = t1valid ? t1 : (T - 1);
    const int  ki0 = keys[b * T + t0];
    const int  ki1 = keys[b * T + t1c];
    const float4* __restrict__ kp0 = (const float4*)(emb + (size_t)ki0 * E);
    const float4* __restrict__ kp1 = (const float4*)(emb + (size_t)ki1 * E);
    __syncthreads();

    // ---- build M[e][j] = w1[64+e][j] - w1[128+e][j] + q[e]*w1[192+e][j] ----
    {
        const int j  = tid & 63;
        const int eq = tid >> 6;            // 2 groups of 32 e-rows
        #pragma unroll
        for (int eo = 0; eo < 32; ++eo) {
            const int e = eq * 32 + eo;
            sBig[e * 64 + j] = w1[(64 + e) * 64 + j] - w1[(128 + e) * 64 + j]
                             + sQ[e] * w1[(192 + e) * 64 + j];
        }
    }
    // ---- u partials: u[j] = b1[j] + sum_e q[e]*(w1[e][j] + w1[128+e][j]) ----
    {
        const int j  = tid & 63;
        const int pt = tid >> 6;            // 0..1
        float a = 0.f;
        #pragma unroll
        for (int eo = 0; eo < 32; ++eo) {
            const int e = pt * 32 + eo;
            a = fmaf(sQ[e], w1[e * 64 + j] + w1[(128 + e) * 64 + j], a);
        }
        sUP[tid] = a;
    }
    __syncthreads();
    if (tid < 64) sU[tid] = b1[tid] + sUP[tid] + sUP[64 + tid];
    __syncthreads();

    // ---- score: two h_pre rows per lane in VGPRs, k streamed from global ----
    float4 acc0[16], acc1[16];
    #pragma unroll
    for (int jq = 0; jq < 16; ++jq) { acc0[jq] = ((const float4*)sU)[jq]; acc1[jq] = acc0[jq]; }

    float4 kv0 = kp0[0];
    float4 kv1 = kp1[0];
    #pragma unroll 1
    for (int c = 0; c < 16; ++c) {
        float4 kn0, kn1;
        if (c < 15) { kn0 = kp0[c + 1]; kn1 = kp1[c + 1]; }   // software prefetch
        const float4* r0 = (const float4*)&sBig[(4 * c + 0) * 64];
        const float4* r1 = (const float4*)&sBig[(4 * c + 1) * 64];
        const float4* r2 = (const float4*)&sBig[(4 * c + 2) * 64];
        const float4* r3 = (const float4*)&sBig[(4 * c + 3) * 64];
        #pragma unroll
        for (int jq = 0; jq < 16; ++jq) {
            const float4 m0 = r0[jq];
            const float4 m1 = r1[jq];
            const float4 m2 = r2[jq];
            const float4 m3 = r3[jq];
            float4 a0 = acc0[jq];
            float4 a1 = acc1[jq];
            a0.x = fmaf(kv0.x, m0.x, a0.x);  a1.x = fmaf(kv1.x, m0.x, a1.x);
            a0.y = fmaf(kv0.x, m0.y, a0.y);  a1.y = fmaf(kv1.x, m0.y, a1.y);
            a0.z = fmaf(kv0.x, m0.z, a0.z);  a1.z = fmaf(kv1.x, m0.z, a1.z);
            a0.w = fmaf(kv0.x, m0.w, a0.w);  a1.w = fmaf(kv1.x, m0.w, a1.w);
            a0.x = fmaf(kv0.y, m1.x, a0.x);  a1.x = fmaf(kv1.y, m1.x, a1.x);
            a0.y = fmaf(kv0.y, m1.y, a0.y);  a1.y = fmaf(kv1.y, m1.y, a1.y);
            a0.z = fmaf(kv0.y, m1.z, a0.z);  a1.z = fmaf(kv1.y, m1.z, a1.z);
            a0.w = fmaf(kv0.y, m1.w, a0.w);  a1.w = fmaf(kv1.y, m1.w, a1.w);
            a0.x = fmaf(kv0.z, m2.x, a0.x);  a1.x = fmaf(kv1.z, m2.x, a1.x);
            a0.y = fmaf(kv0.z, m2.y, a0.y);  a1.y = fmaf(kv1.z, m2.y, a1.y);
            a0.z = fmaf(kv0.z, m2.z, a0.z);  a1.z = fmaf(kv1.z, m2.z, a1.z);
            a0.w = fmaf(kv0.z, m2.w, a0.w);  a1.w = fmaf(kv1.z, m2.w, a1.w);
            a0.x = fmaf(kv0.w, m3.x, a0.x);  a1.x = fmaf(kv1.w, m3.x, a1.x);
            a0.y = fmaf(kv0.w, m3.y, a0.y);  a1.y = fmaf(kv1.w, m3.y, a1.y);
            a0.z = fmaf(kv0.w, m3.z, a0.z);  a1.z = fmaf(kv1.w, m3.z, a1.z);
            a0.w = fmaf(kv0.w, m3.w, a0.w);  a1.w = fmaf(kv1.w, m3.w, a1.w);
            acc0[jq] = a0;
            acc1[jq] = a1;
        }
        kv0 = kn0;
        kv1 = kn1;
    }

    float sc0 = 0.f, sc1 = 0.f;
    #pragma unroll
    for (int jq = 0; jq < 16; ++jq) {
        const float4 wv = ((const float4*)sW2)[jq];
        sc0 = fmaf(fmaxf(acc0[jq].x, 0.f), wv.x, sc0);
        sc0 = fmaf(fmaxf(acc0[jq].y, 0.f), wv.y, sc0);
        sc0 = fmaf(fmaxf(acc0[jq].z, 0.f), wv.z, sc0);
        sc0 = fmaf(fmaxf(acc0[jq].w, 0.f), wv.w, sc0);
        sc1 = fmaf(fmaxf(acc1[jq].x, 0.f), wv.x, sc1);
        sc1 = fmaf(fmaxf(acc1[jq].y, 0.f), wv.y, sc1);
        sc1 = fmaf(fmaxf(acc1[jq].z, 0.f), wv.z, sc1);
        sc1 = fmaf(fmaxf(acc1[jq].w, 0.f), wv.w, sc1);
    }
    const float score0 = sc0 + b2v;
    const float score1 = t1valid ? (sc1 + b2v) : -1e30f;

    // ---- softmax over t (2 scores per lane, 2 waves) ----
    float m = fmaxf(score0, score1);
    #pragma unroll
    for (int off = 32; off > 0; off >>= 1) m = fmaxf(m, __shfl_xor(m, off));
    if (lane == 0) sRed[wid] = m;
    __syncthreads();
    const float gmax = fmaxf(sRed[0], sRed[1]);
    const float p0 = __expf(score0 - gmax);
    const float p1 = t1valid ? __expf(score1 - gmax) : 0.f;
    float s = p0 + p1;
    #pragma unroll
    for (int off = 32; off > 0; off >>= 1) s += __shfl_xor(s, off);
    if (lane == 0) sRed[2 + wid] = s;
    __syncthreads();
    const float gsum = sRed[2] + sRed[3];
    const float w0 = p0 / gsum;
    const float w1w = p1 / gsum;     // 0 for invalid t1

    // ---- interest[e] = sum_t w[t]*k[t][e]; lane folds its 2 t's, 2 phases ----
    for (int r = 0; r < 2; ++r) {
        if (wid == r) {
            float* row = &sBig[lane * 65];
            #pragma unroll
            for (int c = 0; c < 16; ++c) {
                const float4 a = kp0[c];
                const float4 bb = kp1[c];
                const float vx = w0 * a.x + w1w * bb.x;
                const float vy = w0 * a.y + w1w * bb.y;
                const float vz = w0 * a.z + w1w * bb.z;
                const float vw = w0 * a.w + w1w * bb.w;
                if (r == 0) {
                    row[4 * c + 0] = vx;
                    row[4 * c + 1] = vy;
                    row[4 * c + 2] = vz;
                    row[4 * c + 3] = vw;
                } else {
                    row[4 * c + 0] += vx;
                    row[4 * c + 1] += vy;
                    row[4 * c + 2] += vz;
                    row[4 * c + 3] += vw;
                }
            }
        }
        __syncthreads();
    }
    if (tid < 64) {
        float a = 0.f;
        #pragma unroll 8
        for (int l = 0; l < 64; ++l) a += sBig[l * 65 + tid];
        sInt[tid] = a;
    }
    __syncthreads();

    // ---- deep MLP: 64 -> 128 -> 64 -> 1 ----
    {
        float a = db1[tid];
        #pragma unroll 8
        for (int e = 0; e < 64; ++e) a = fmaf(sInt[e], dw1[e * 128 + tid], a);
        sD1[tid] = fmaxf(a, 0.f);
    }
    __syncthreads();
    if (tid < 64) {
        float a = db2[tid];
        #pragma unroll 8
        for (int i = 0; i < 128; ++i) a = fmaf(sD1[i], dw2[i * 64 + tid], a);
        sD2[tid] = fmaxf(a, 0.f);
    }
    __syncthreads();
    if (tid < 64) {
        float v = sD2[tid] * ow[tid];
        #pragma unroll
        for (int off = 32; off > 0; off >>= 1) v += __shfl_xor(v, off);
        if (tid == 0) out[b] = 1.f / (1.f + __expf(-(v + ob[0])));
    }
}

extern "C" void kernel_launch(void* const* d_in, const int* in_sizes, int n_in,
                              void* d_out, int out_size, void* d_ws, size_t ws_size,
                              hipStream_t stream) {
    const int*   query = (const int*)d_in[0];
    const int*   keys  = (const int*)d_in[1];
    const float* emb   = (const float*)d_in[2];
    const float* w1    = (const float*)d_in[3];
    const float* b1    = (const float*)d_in[4];
    const float* w2    = (const float*)d_in[5];
    const float* b2    = (const float*)d_in[6];
    const float* dw1   = (const float*)d_in[7];
    const float* db1   = (const float*)d_in[8];
    const float* dw2   = (const float*)d_in[9];
    const float* db2   = (const float*)d_in[10];
    const float* ow    = (const float*)d_in[11];
    const float* ob    = (const float*)d_in[12];
    float* out = (float*)d_out;
    const int B = in_sizes[0];

    din_kernel<<<B, BDIM, 0, stream>>>(query, keys, emb, w1, b1, w2, b2,
                                       dw1, db1, dw2, db2, ow, ob, out);
}

// Round 4
// 170.250 us; speedup vs baseline: 1.5340x; 1.5340x over previous
//
#include <hip/hip_runtime.h>

#define T 200
#define E 64
#define TPAD 256
#define ROW 72          // bf16 elems per padded LDS row (144 B, 16B-aligned, bank-uniform)
#define BDIM 256

typedef __bf16 bf16_t;
typedef __bf16 bf16x8 __attribute__((ext_vector_type(8)));
typedef float f32x4 __attribute__((ext_vector_type(4)));

// ---- pre-pass: emb fp32 -> bf16 into workspace (halves gather bytes) ----
__global__ __launch_bounds__(256) void emb_cvt(const float* __restrict__ src,
                                               bf16_t* __restrict__ dst, int n8) {
    const int i = blockIdx.x * 256 + threadIdx.x;
    if (i >= n8) return;
    const float4* s = (const float4*)src + (size_t)i * 2;
    const float4 a = s[0], b = s[1];
    union { bf16_t h[8]; uint4 v; } u;
    u.h[0] = (bf16_t)a.x; u.h[1] = (bf16_t)a.y; u.h[2] = (bf16_t)a.z; u.h[3] = (bf16_t)a.w;
    u.h[4] = (bf16_t)b.x; u.h[5] = (bf16_t)b.y; u.h[6] = (bf16_t)b.z; u.h[7] = (bf16_t)b.w;
    ((uint4*)dst)[i] = u.v;
}

__global__ __launch_bounds__(BDIM, 3) void din_kernel(
    const int* __restrict__ query,
    const int* __restrict__ keys,
    const float* __restrict__ embf,
    const bf16_t* __restrict__ emb16,
    const int use16,
    const float* __restrict__ w1,
    const float* __restrict__ b1,
    const float* __restrict__ w2,
    const float* __restrict__ b2,
    const float* __restrict__ dw1,
    const float* __restrict__ db1,
    const float* __restrict__ dw2,
    const float* __restrict__ db2,
    const float* __restrict__ ow,
    const float* __restrict__ ob,
    float* __restrict__ out)
{
    // sRaw: phase 1 = sTmp (fp32 M, 64x65), phase 2+ = sK (bf16 256x72 A-tiles)
    __shared__ __align__(16) char sRaw[TPAD * ROW * 2];
    __shared__ __align__(16) bf16_t sMt[64 * ROW];      // B-operand: row j, cols e
    __shared__ float sU[64];
    __shared__ float sUP[256];
    __shared__ float sW2f[64];
    __shared__ float sWgt[256];                          // scores, then softmax weights
    __shared__ float sQf[64];
    __shared__ __align__(16) char sQtmp[128];
    __shared__ float sRed[8];
    __shared__ float sInt[64];
    __shared__ float sD1[128];
    __shared__ float sD2[64];

    const int tid  = threadIdx.x;
    const int lane = tid & 63;
    const int wid  = tid >> 6;
    const int b    = blockIdx.x;
    const float b2v = b2[0];

    // ---- issue long-latency gathers first: this thread's key row (t = tid) ----
    uint4 kr[8];
    if (tid < T) {
        const int ki = keys[b * T + tid];
        if (use16) {
            const uint4* kp = (const uint4*)(emb16 + (size_t)ki * E);
            #pragma unroll
            for (int c = 0; c < 8; ++c) kr[c] = kp[c];
        } else {
            const float4* kp = (const float4*)(embf + (size_t)ki * E);
            #pragma unroll
            for (int c = 0; c < 8; ++c) {
                const float4 x = kp[2 * c], y = kp[2 * c + 1];
                union { bf16_t h[8]; uint4 v; } u;
                u.h[0] = (bf16_t)x.x; u.h[1] = (bf16_t)x.y; u.h[2] = (bf16_t)x.z; u.h[3] = (bf16_t)x.w;
                u.h[4] = (bf16_t)y.x; u.h[5] = (bf16_t)y.y; u.h[6] = (bf16_t)y.z; u.h[7] = (bf16_t)y.w;
                kr[c] = u.v;
            }
        }
    } else {
        #pragma unroll
        for (int c = 0; c < 8; ++c) kr[c] = make_uint4(0u, 0u, 0u, 0u);
    }

    // ---- query row -> LDS ----
    const int qi = query[b];
    if (tid < 8) {
        uint4 qv;
        if (use16) {
            qv = ((const uint4*)(emb16 + (size_t)qi * E))[tid];
        } else {
            const float4 x = ((const float4*)(embf + (size_t)qi * E))[2 * tid];
            const float4 y = ((const float4*)(embf + (size_t)qi * E))[2 * tid + 1];
            union { bf16_t h[8]; uint4 v; } u;
            u.h[0] = (bf16_t)x.x; u.h[1] = (bf16_t)x.y; u.h[2] = (bf16_t)x.z; u.h[3] = (bf16_t)x.w;
            u.h[4] = (bf16_t)y.x; u.h[5] = (bf16_t)y.y; u.h[6] = (bf16_t)y.z; u.h[7] = (bf16_t)y.w;
            qv = u.v;
        }
        ((uint4*)sQtmp)[tid] = qv;
    }
    if (tid < 64) sW2f[tid] = w2[tid];
    __syncthreads();
    if (tid < 64) sQf[tid] = (float)((const bf16_t*)sQtmp)[tid];
    __syncthreads();

    // ---- pass 1: M (fp32, j-major scratch) + u partials; coalesced w1 reads ----
    {
        float* sTmp = (float*)sRaw;
        const int j = tid & 63, ec = tid >> 6;
        float au = 0.f;
        #pragma unroll
        for (int eo = 0; eo < 16; ++eo) {
            const int e = ec * 16 + eo;
            const float w1a = w1[e * 64 + j];
            const float w1b = w1[(64 + e) * 64 + j];
            const float w1c = w1[(128 + e) * 64 + j];
            const float w1d = w1[(192 + e) * 64 + j];
            sTmp[e * 65 + j] = w1b - w1c + sQf[e] * w1d;
            au = fmaf(sQf[e], w1a + w1c, au);
        }
        sUP[tid] = au;
    }
    __syncthreads();
    // ---- pass 2: transpose+cvt M -> sMt (bf16, row j, cols e); u combine ----
    {
        const float* sTmp = (const float*)sRaw;
        const int e = tid & 63, jc = tid >> 6;
        #pragma unroll
        for (int jo = 0; jo < 16; ++jo) {
            const int j = jc * 16 + jo;
            sMt[j * ROW + e] = (bf16_t)sTmp[e * 65 + j];
        }
    }
    if (tid < 64) sU[tid] = b1[tid] + sUP[tid] + sUP[64 + tid] + sUP[128 + tid] + sUP[192 + tid];
    __syncthreads();

    // ---- stage k rows into sK (overwrites sTmp region) ----
    bf16_t* sK = (bf16_t*)sRaw;
    {
        uint4* dst = (uint4*)(sK + tid * ROW);
        #pragma unroll
        for (int c = 0; c < 8; ++c) dst[c] = kr[c];
    }
    __syncthreads();

    // ---- MFMA score GEMM: h_pre = u + k(256x64) * M(64x64), bf16 in fp32 out ----
    {
        const int n    = lane & 15;
        const int quad = lane >> 4;
        float w2v[4], uv[4];
        bf16x8 bF[4][2];
        #pragma unroll
        for (int nt = 0; nt < 4; ++nt) {
            w2v[nt] = sW2f[nt * 16 + n];
            uv[nt]  = sU[nt * 16 + n];
            bF[nt][0] = *(const bf16x8*)&sMt[(nt * 16 + n) * ROW + quad * 8];
            bF[nt][1] = *(const bf16x8*)&sMt[(nt * 16 + n) * ROW + 32 + quad * 8];
        }
        #pragma unroll
        for (int i = 0; i < 4; ++i) {
            const int mt = wid * 4 + i;
            const bf16x8 a0 = *(const bf16x8*)&sK[(mt * 16 + n) * ROW + quad * 8];
            const bf16x8 a1 = *(const bf16x8*)&sK[(mt * 16 + n) * ROW + 32 + quad * 8];
            float s0 = 0.f, s1 = 0.f, s2 = 0.f, s3 = 0.f;
            #pragma unroll
            for (int nt = 0; nt < 4; ++nt) {
                f32x4 acc = { uv[nt], uv[nt], uv[nt], uv[nt] };
                acc = __builtin_amdgcn_mfma_f32_16x16x32_bf16(a0, bF[nt][0], acc, 0, 0, 0);
                acc = __builtin_amdgcn_mfma_f32_16x16x32_bf16(a1, bF[nt][1], acc, 0, 0, 0);
                s0 = fmaf(fmaxf(acc[0], 0.f), w2v[nt], s0);
                s1 = fmaf(fmaxf(acc[1], 0.f), w2v[nt], s1);
                s2 = fmaf(fmaxf(acc[2], 0.f), w2v[nt], s2);
                s3 = fmaf(fmaxf(acc[3], 0.f), w2v[nt], s3);
            }
            // reduce over the 16 col-lanes (n) within each quad
            #pragma unroll
            for (int off = 1; off < 16; off <<= 1) {
                s0 += __shfl_xor(s0, off);
                s1 += __shfl_xor(s1, off);
                s2 += __shfl_xor(s2, off);
                s3 += __shfl_xor(s3, off);
            }
            if (n == 0) {
                const int base = mt * 16 + quad * 4;
                sWgt[base + 0] = s0;
                sWgt[base + 1] = s1;
                sWgt[base + 2] = s2;
                sWgt[base + 3] = s3;
            }
        }
    }
    __syncthreads();

    // ---- softmax over t (t = tid) ----
    {
        const float score = (tid < T) ? (sWgt[tid] + b2v) : -1e30f;
        float m = score;
        #pragma unroll
        for (int off = 32; off > 0; off >>= 1) m = fmaxf(m, __shfl_xor(m, off));
        if (lane == 0) sRed[wid] = m;
        __syncthreads();
        const float gmax = fmaxf(fmaxf(sRed[0], sRed[1]), fmaxf(sRed[2], sRed[3]));
        const float p = (tid < T) ? __expf(score - gmax) : 0.f;
        float s = p;
        #pragma unroll
        for (int off = 32; off > 0; off >>= 1) s += __shfl_xor(s, off);
        if (lane == 0) sRed[4 + wid] = s;
        __syncthreads();
        const float gsum = sRed[4] + sRed[5] + sRed[6] + sRed[7];
        sWgt[tid] = p / gsum;          // 0 for padded t
    }
    __syncthreads();

    // ---- interest[e] = sum_t w[t] * k[t][e]  (bf16 k from LDS) ----
    {
        const int e = tid & 63, ch = tid >> 6;
        float a = 0.f;
        #pragma unroll 8
        for (int tt = 0; tt < 64; ++tt) {
            const int t = ch * 64 + tt;
            a = fmaf(sWgt[t], (float)sK[t * ROW + e], a);
        }
        sUP[tid] = a;
    }
    __syncthreads();
    if (tid < 64) sInt[tid] = sUP[tid] + sUP[64 + tid] + sUP[128 + tid] + sUP[192 + tid];
    __syncthreads();

    // ---- deep MLP: 64 -> 128 -> 64 -> 1 ----
    if (tid < 128) {
        float a = db1[tid];
        #pragma unroll 8
        for (int e = 0; e < 64; ++e) a = fmaf(sInt[e], dw1[e * 128 + tid], a);
        sD1[tid] = fmaxf(a, 0.f);
    }
    __syncthreads();
    if (tid < 64) {
        float a = db2[tid];
        #pragma unroll 8
        for (int i = 0; i < 128; ++i) a = fmaf(sD1[i], dw2[i * 64 + tid], a);
        sD2[tid] = fmaxf(a, 0.f);
    }
    __syncthreads();
    if (tid < 64) {
        float v = sD2[tid] * ow[tid];
        #pragma unroll
        for (int off = 32; off > 0; off >>= 1) v += __shfl_xor(v, off);
        if (tid == 0) out[b] = 1.f / (1.f + __expf(-(v + ob[0])));
    }
}

extern "C" void kernel_launch(void* const* d_in, const int* in_sizes, int n_in,
                              void* d_out, int out_size, void* d_ws, size_t ws_size,
                              hipStream_t stream) {
    const int*   query = (const int*)d_in[0];
    const int*   keys  = (const int*)d_in[1];
    const float* embf  = (const float*)d_in[2];
    const float* w1    = (const float*)d_in[3];
    const float* b1    = (const float*)d_in[4];
    const float* w2    = (const float*)d_in[5];
    const float* b2    = (const float*)d_in[6];
    const float* dw1   = (const float*)d_in[7];
    const float* db1   = (const float*)d_in[8];
    const float* dw2   = (const float*)d_in[9];
    const float* db2   = (const float*)d_in[10];
    const float* ow    = (const float*)d_in[11];
    const float* ob    = (const float*)d_in[12];
    float* out = (float*)d_out;
    const int B       = in_sizes[0];
    const int embElems = in_sizes[2];                  // VOCAB * E
    const int use16   = (ws_size >= (size_t)embElems * 2) ? 1 : 0;
    bf16_t* emb16 = (bf16_t*)d_ws;

    if (use16) {
        const int n8 = embElems / 8;
        emb_cvt<<<(n8 + 255) / 256, 256, 0, stream>>>(embf, emb16, n8);
    }
    din_kernel<<<B, BDIM, 0, stream>>>(query, keys, embf, emb16, use16,
                                       w1, b1, w2, b2, dw1, db1, dw2, db2, ow, ob, out);
}